// Round 5
// baseline (197.252 us; speedup 1.0000x reference)
//
#include <hip/hip_runtime.h>

// Deinterleave x[B,C,H,W] (fp32, H=W=256) into 4 quadrant tensors:
//   ll = x[:,:,0::2,0::2], lh = x[:,:,0::2,1::2],
//   hl = x[:,:,1::2,0::2], hh = x[:,:,1::2,1::2]
// d_out = [ll | lh | hl | hh] flat, each of size B*C*128*128 floats.
//
// One wave-iteration = 4 consecutive input rows (4 KB), loaded as four
// 1KB wave-contiguous float4 segments.
//
// Key trick: lane pair (2j, 2j+1) holds 8 consecutive floats (cols
// 8j..8j+7) of a row. One adjacent-lane swap (DPP quad_perm [1,0,3,2],
// pure VALU, no LDS) of the 2 "wrong-parity" floats gives:
//   even lane: {c8j, c8j+2, c8j+4, c8j+6} = even-col chunk j (16B)
//   odd  lane: {c8j+1, c8j+3, c8j+5, c8j+7} = odd-col chunk j (16B)
// so every store is global_store_dwordx4 (16B/lane, max width), with even
// lanes writing a dense 512B segment of ll/hl and odd lanes a dense 512B
// segment of lh/hh.

typedef float f32x4 __attribute__((ext_vector_type(4)));

__device__ __forceinline__ float dpp_swap_adj(float x) {
    // quad_perm [1,0,3,2] = 1 | 0<<2 | 3<<4 | 2<<6 = 0xB1: swap lanes 0<->1, 2<->3
    return __int_as_float(__builtin_amdgcn_update_dpp(
        0, __float_as_int(x), 0xB1, 0xF, 0xF, true));
}

__global__ __launch_bounds__(256) void deinterleave2x2_kernel(
    const f32x4* __restrict__ in,    // input viewed as 16B vectors
    float* __restrict__ out,         // base of concatenated outputs
    size_t nitems,                   // total work items = N/16
    size_t outsz)                    // elements per output tensor
{
    const size_t stride = (size_t)gridDim.x * blockDim.x;
    for (size_t t = (size_t)blockIdx.x * blockDim.x + threadIdx.x;
         t < nitems; t += stride) {
        const int    l   = (int)(t & 63);   // lane within wave
        const size_t g   = t >> 6;          // group = 4 consecutive rows
        const size_t rp  = (g & 63) * 2;    // first output row within image
        const size_t img = g >> 6;          // which (b,c) image

        const size_t ib = 256 * g + l;      // input f4 base for this lane
        const f32x4 v0 = in[ib];            // row 4G   (even)
        const f32x4 v1 = in[ib + 64];       // row 4G+1 (odd)
        const f32x4 v2 = in[ib + 128];      // row 4G+2 (even)
        const f32x4 v3 = in[ib + 192];      // row 4G+3 (odd)

        const bool evl = (l & 1) == 0;      // even lane of the pair
        const int  j   = l >> 1;            // chunk index 0..31

        // lane's 16B output chunk position within its quadrant image
        const size_t off = img * (size_t)(128 * 128) + rp * 128 + 4 * (size_t)j;
        // even lane -> ll/hl stream; odd lane -> lh/hh stream
        float* pA = out + (evl ? (size_t)0 : outsz) + off;  // even rows: ll | lh
        float* pB = pA + 2 * outsz;                         // odd rows:  hl | hh

        auto proc = [&](f32x4 v, float* dst) {
            // send partner what it needs: even lane sends its odd cols,
            // odd lane sends its even cols
            float s0 = evl ? v.y : v.x;
            float s1 = evl ? v.w : v.z;
            float r0 = dpp_swap_adj(s0);
            float r1 = dpp_swap_adj(s1);
            f32x4 res;
            res.x = evl ? v.x : r0;
            res.y = evl ? v.z : r1;
            res.z = evl ? r0 : v.y;
            res.w = evl ? r1 : v.w;
            __builtin_nontemporal_store(res, reinterpret_cast<f32x4*>(dst));
        };

        proc(v0, pA);          // row 4G   -> ll/lh, out row rp
        proc(v1, pB);          // row 4G+1 -> hl/hh, out row rp
        proc(v2, pA + 128);    // row 4G+2 -> ll/lh, out row rp+1
        proc(v3, pB + 128);    // row 4G+3 -> hl/hh, out row rp+1
    }
}

extern "C" void kernel_launch(void* const* d_in, const int* in_sizes, int n_in,
                              void* d_out, int out_size, void* d_ws, size_t ws_size,
                              hipStream_t stream) {
    const float* x = (const float*)d_in[0];
    float* out = (float*)d_out;

    const size_t total  = (size_t)in_sizes[0];      // B*C*H*W = 8*256*256*256
    const size_t nitems = total >> 4;               // 16 floats per work item
    const size_t outsz  = total >> 2;               // each output = total/4

    const int threads = 256;
    const int blocks  = 2048;                        // 8 waves/SIMD across 256 CUs

    deinterleave2x2_kernel<<<blocks, threads, 0, stream>>>(
        reinterpret_cast<const f32x4*>(x), out, nitems, outsz);
}

// Round 6
// 196.911 us; speedup vs baseline: 1.0017x; 1.0017x over previous
//
#include <hip/hip_runtime.h>

// Deinterleave x[B,C,H,W] (fp32, H=W=256) into 4 quadrant tensors:
//   ll = x[:,:,0::2,0::2], lh = x[:,:,0::2,1::2],
//   hl = x[:,:,1::2,0::2], hh = x[:,:,1::2,1::2]
// d_out = [ll | lh | hl | hh] flat, each of size B*C*128*128 floats.
//
// One wave-iteration = 4 consecutive input rows (4 KB):
//   loads:  4x dense 1KB wave segments (16B/lane), identical to a copy kernel
//   repack: per-wave 4KB LDS stage (no barrier; intra-wave only).
//           XOR swizzle i^((i>>3)&7) keeps the stride-2-f4 reads conflict-free.
//   stores: 4x dense 1KB wave segments (16B/lane), each instruction entirely
//           within ONE quadrant -> copy-identical store shape, max DRAM burst.
//
// Lane l (m = l&31, h = l>>5) reads LDS f4s {2m, 2m+1} of input rows 2h and
// 2h+1, extracts even/odd columns in-lane, and stores output row 2(g&63)+h
// of each quadrant: lanes 0..31 cover out-row G, lanes 32..63 out-row G+1,
// so each store is 1KB contiguous in its quadrant.

typedef float f32x4 __attribute__((ext_vector_type(4)));

__device__ __forceinline__ int swz(int i) { return i ^ ((i >> 3) & 7); }

__global__ __launch_bounds__(256) void deinterleave2x2_kernel(
    const f32x4* __restrict__ in,    // input viewed as 16B vectors
    float* __restrict__ out,         // base of concatenated outputs
    size_t nitems,                   // total work items = N/16
    size_t outsz)                    // elements per output tensor
{
    __shared__ f32x4 lds[4 * 256];   // 4 waves x 4KB, disjoint per wave
    const int tid = (int)threadIdx.x;
    const int l   = tid & 63;        // lane within wave
    const int m   = l & 31;
    const int h   = l >> 5;
    f32x4* wl = &lds[(tid >> 6) * 256];

    const size_t stride = (size_t)gridDim.x * blockDim.x;
    for (size_t t = (size_t)blockIdx.x * blockDim.x + threadIdx.x;
         t < nitems; t += stride) {
        const size_t g   = t >> 6;          // group of 4 input rows
        const size_t img = g >> 6;          // which (b,c) image
        const size_t G2  = (g & 63) * 2;    // base output row in quadrant

        // Dense copy-style loads: rows 4g..4g+3.
        const size_t ib = 256 * g;
        const f32x4 v0 = in[ib + l];
        const f32x4 v1 = in[ib + 64 + l];
        const f32x4 v2 = in[ib + 128 + l];
        const f32x4 v3 = in[ib + 192 + l];

        // Stage in per-wave LDS (swizzled), then cross-lane gather.
        wl[swz(l)]       = v0;
        wl[swz(64 + l)]  = v1;
        wl[swz(128 + l)] = v2;
        wl[swz(192 + l)] = v3;

        // Even input rows (0 or 2) -> ll/lh; odd rows (1 or 3) -> hl/hh.
        const f32x4 A0 = wl[swz(128 * h + 2 * m)];
        const f32x4 A1 = wl[swz(128 * h + 2 * m + 1)];
        const f32x4 B0 = wl[swz(128 * h + 64 + 2 * m)];
        const f32x4 B1 = wl[swz(128 * h + 64 + 2 * m + 1)];

        f32x4 ll; ll.x = A0.x; ll.y = A0.z; ll.z = A1.x; ll.w = A1.z;
        f32x4 lh; lh.x = A0.y; lh.y = A0.w; lh.z = A1.y; lh.w = A1.w;
        f32x4 hl; hl.x = B0.x; hl.y = B0.z; hl.z = B1.x; hl.w = B1.z;
        f32x4 hh; hh.x = B0.y; hh.y = B0.w; hh.z = B1.y; hh.w = B1.w;

        const size_t off = img * (size_t)(128 * 128) + (G2 + h) * 128 + 4 * (size_t)m;

        __builtin_nontemporal_store(ll, reinterpret_cast<f32x4*>(out + off));
        __builtin_nontemporal_store(lh, reinterpret_cast<f32x4*>(out + outsz + off));
        __builtin_nontemporal_store(hl, reinterpret_cast<f32x4*>(out + 2 * outsz + off));
        __builtin_nontemporal_store(hh, reinterpret_cast<f32x4*>(out + 3 * outsz + off));
    }
}

extern "C" void kernel_launch(void* const* d_in, const int* in_sizes, int n_in,
                              void* d_out, int out_size, void* d_ws, size_t ws_size,
                              hipStream_t stream) {
    const float* x = (const float*)d_in[0];
    float* out = (float*)d_out;

    const size_t total  = (size_t)in_sizes[0];      // B*C*H*W = 8*256*256*256
    const size_t nitems = total >> 4;               // 16 floats per work item
    const size_t outsz  = total >> 2;               // each output = total/4

    const int threads = 256;
    const int blocks  = 2048;

    deinterleave2x2_kernel<<<blocks, threads, 0, stream>>>(
        reinterpret_cast<const f32x4*>(x), out, nitems, outsz);
}